// Round 2
// 177.560 us; speedup vs baseline: 1.3943x; 1.3943x over previous
//
#include <hip/hip_runtime.h>
#include <cstdint>

#pragma clang fp contract(off)

#define BS   128
#define NQ   900
#define NC   91
#define NQC  (NQ * NC)   // 81900
#define Q4   (NQC / 4)   // 20475
#define THIRD (NQC / 3)  // 27300
#define T4   (THIRD / 4) // 6825
#define PRE  10000
#define POST 100
#define RUNSZ 4096
#define RUNS 3
#define KSTRIDE (RUNS * RUNSZ)    // 12288 keys per image
#define TBITS 13
#define TBINS (1 << TBITS)
#define TSHIFT (32 - TBITS)
#define K_WIN 16
#define M_CAP 11000

typedef unsigned long long ull;

// ---- workspace layout (bytes) ----
#define WS_THR    0            // 128*4
#define WS_KEYS   8192         // 128*12288*8 = 12.6 MB

__device__ __forceinline__ uint32_t fkey(float f) {
    uint32_t b = __float_as_uint(f);
    return (b & 0x80000000u) ? ~b : (b | 0x80000000u);
}
__device__ __forceinline__ uint32_t qclamp(uint32_t q) { return (q < NQ) ? q : (NQ - 1); }

// ============ Kernel 1: per-image LDS histogram -> single threshold T_lo ============
__global__ void __launch_bounds__(1024) k_select(const float* __restrict__ logits,
                                                 uint32_t* __restrict__ thr) {
    int img = blockIdx.x;
    const int tid = threadIdx.x;
    __shared__ uint32_t hist[TBINS];   // 32 KB
    __shared__ uint32_t part[1024];
    __shared__ uint32_t part2[32];
    __shared__ uint32_t sTlo, sBlo, sCumAboveLo, sM;
    for (int i = tid; i < TBINS; i += 1024) hist[i] = 0u;
    __syncthreads();
    const float4* lg4 = (const float4*)(logits + (size_t)img * NQC);
    for (int i = tid; i < Q4; i += 1024) {
        float4 v = lg4[i];
        atomicAdd(&hist[fkey(v.x) >> TSHIFT], 1u);
        atomicAdd(&hist[fkey(v.y) >> TSHIFT], 1u);
        atomicAdd(&hist[fkey(v.z) >> TSHIFT], 1u);
        atomicAdd(&hist[fkey(v.w) >> TSHIFT], 1u);
    }
    __syncthreads();
    {
        uint32_t s = 0;
        int base = tid * (TBINS / 1024);
        for (int j = 0; j < TBINS / 1024; ++j) s += hist[base + j];
        part[tid] = s;
    }
    __syncthreads();
    if (tid < 32) {
        uint32_t s2 = 0;
        for (int j = 0; j < 32; ++j) s2 += part[tid * 32 + j];
        part2[tid] = s2;
    }
    __syncthreads();
    if (tid == 0) {
        uint32_t cum = 0; int w = 31;
        for (; w > 0; --w) { if (cum + part2[w] >= PRE) break; cum += part2[w]; }
        int t = w * 32 + 31;
        for (; t > w * 32; --t) { if (cum + part[t] >= PRE) break; cum += part[t]; }
        int b = t * (TBINS / 1024) + (TBINS / 1024 - 1);
        for (; b > t * (TBINS / 1024); --b) { if (cum + hist[b] >= PRE) break; cum += hist[b]; }
        sBlo = (uint32_t)b;
        sCumAboveLo = cum;
        sM = cum + hist[b];
        sTlo = ((uint32_t)b) << TSHIFT;
    }
    __syncthreads();
    if (sM > M_CAP) {   // rare fallback: refine Tlo by 8 bits
        uint32_t P = sBlo;
        for (int i = tid; i < 256; i += 1024) part[i] = 0u;
        __syncthreads();
        for (int i = tid; i < Q4; i += 1024) {
            float4 v = lg4[i];
            uint32_t u;
            u = fkey(v.x); if ((u >> TSHIFT) == P) atomicAdd(&part[(u >> (TSHIFT - 8)) & 0xFFu], 1u);
            u = fkey(v.y); if ((u >> TSHIFT) == P) atomicAdd(&part[(u >> (TSHIFT - 8)) & 0xFFu], 1u);
            u = fkey(v.z); if ((u >> TSHIFT) == P) atomicAdd(&part[(u >> (TSHIFT - 8)) & 0xFFu], 1u);
            u = fkey(v.w); if ((u >> TSHIFT) == P) atomicAdd(&part[(u >> (TSHIFT - 8)) & 0xFFu], 1u);
        }
        __syncthreads();
        if (tid == 0) {
            uint32_t K = PRE - sCumAboveLo;
            uint32_t cum = 0; int x = 255;
            for (; x > 0; --x) { if (cum + part[x] >= K) break; cum += part[x]; }
            sTlo = (P << TSHIFT) | (((uint32_t)x) << (TSHIFT - 8));
        }
        __syncthreads();
    }
    if (tid == 0) thr[img] = sTlo;
}

// ============ Kernel 2: fused compact+sort (bitonic, wave-chunked) ============
// j-steps with j<=128 stay inside a wave-owned 256-elem chunk: wave64 lockstep +
// per-wave in-order LDS => no __syncthreads needed. Compiler fences (zero-cost
// asm memory clobbers) pin the LDS op order. Only j>=256 steps are cross-wave.
// Barriers: 79 -> 16.
__global__ void __launch_bounds__(1024) k_sortcompact(const float* __restrict__ logits,
                                                      const uint32_t* __restrict__ thr,
                                                      ull* __restrict__ keys) {
    int img = blockIdx.y;
    int run = blockIdx.x;
    const int tid = threadIdx.x;
    const int lane = tid & 63;
    __shared__ ull sh[RUNSZ];   // 32 KB
    __shared__ uint32_t sCnt;
    if (tid == 0) sCnt = 0u;
    __syncthreads();
    const uint32_t Tlo = thr[img];
    const float4* lg4 = (const float4*)(logits + (size_t)img * NQC) + (size_t)run * T4;
    const int fbase = run * THIRD;
    for (int i0 = 0; i0 < T4; i0 += 1024) {
        int i = i0 + tid;
        bool inb = (i < T4);
        float4 v = inb ? lg4[i] : make_float4(0.f, 0.f, 0.f, 0.f);
        float comp[4] = {v.x, v.y, v.z, v.w};
        #pragma unroll
        for (int c = 0; c < 4; ++c) {
            uint32_t u = inb ? fkey(comp[c]) : 0u;
            bool pass = inb && (u >= Tlo);
            ull m = __ballot(pass);
            uint32_t below = (uint32_t)__popcll(m & ((1ull << lane) - 1ull));
            uint32_t wtot = (uint32_t)__popcll(m);
            uint32_t wb = 0u;
            if (lane == 0 && wtot) wb = atomicAdd(&sCnt, wtot);
            wb = __shfl(wb, 0, 64);
            if (pass) {
                uint32_t p = wb + below;
                uint32_t fi = (uint32_t)(fbase + i * 4 + c);
                if (p < RUNSZ) sh[p] = ((ull)u << 32) | (ull)(0xFFFFFFFFu - fi);
            }
        }
    }
    __syncthreads();
    uint32_t n = sCnt; if (n > RUNSZ) n = RUNSZ;
    for (int i = tid; i < RUNSZ; i += 1024) if (i >= (int)n) sh[i] = 0ull;
    __syncthreads();

    const int wv = tid >> 6;
    const int cbase = wv << 8;     // wave-owned 256-element chunk
    for (int k = 2; k <= RUNSZ; k <<= 1) {
        if (k >= 512) {
            __syncthreads();       // make previous within-chunk writes visible
            for (int j = k >> 1; j >= 256; j >>= 1) {
                for (int t = tid; t < RUNSZ / 2; t += 1024) {
                    int i = ((t & ~(j - 1)) << 1) | (t & (j - 1));
                    int ixj = i | j;
                    ull a = sh[i], b = sh[ixj];
                    bool sw = ((i & k) == 0) ? (a < b) : (a > b);
                    if (sw) { sh[i] = b; sh[ixj] = a; }
                }
                __syncthreads();
            }
        }
        int j0 = ((k >> 1) < 128) ? (k >> 1) : 128;
        for (int j = j0; j >= 1; j >>= 1) {
            // 128 pairs per chunk; reps touch disjoint elements; no barrier
            #pragma unroll
            for (int rep = 0; rep < 2; ++rep) {
                int pl = (rep << 6) | lane;
                int io = ((pl & ~(j - 1)) << 1) | (pl & (j - 1));
                int i = cbase | io;
                int ixj = i | j;
                ull a = sh[i], b = sh[ixj];
                bool sw = ((i & k) == 0) ? (a < b) : (a > b);
                if (sw) { sh[i] = b; sh[ixj] = a; }
            }
            asm volatile("" ::: "memory");   // pin LDS op order across j-steps
        }
    }
    asm volatile("" ::: "memory");
    // wave-local writeout of own chunk (last writer == this wave => no barrier)
    ull* base = keys + (size_t)img * KSTRIDE + (size_t)run * RUNSZ;
    #pragma unroll
    for (int rep = 0; rep < 4; ++rep) {
        int i = cbase | (rep << 6) | lane;
        base[i] = sh[i];
    }
}

// ============ Kernel 3: 3-way rank-merge + LAZY windowed greedy NMS ============
// Rank merge: breadth-first interleaved binary searches (8 concurrent, 12 fixed
// steps + 1 correction) instead of 24 dependent-chain searches.
// Greedy: each candidate examined ONCE in rank order; accept iff no offset-exact
// IoU>0.7 conflict with an already-accepted SAME-CLASS pick (<=100 entries).
// No active bitmask, no class buckets, no 10000-wide suppression scans.
// Cross-class suppression impossible (offset bands => IoU <= 1/3 < 0.7), and
// same-class tests replicate the reference's (raw+class*offD) arithmetic
// operand-for-operand => bit-exact vs reference.
__global__ void __launch_bounds__(1024) k_nms(const ull* __restrict__ keys,
                                              const float* __restrict__ logits,
                                              const float* __restrict__ pred_boxes,
                                              const float* __restrict__ target_sizes,
                                              float* __restrict__ out) {
    int img = blockIdx.x;
    const int tid = threadIdx.x;
    const int lane = tid & 63;
    const int wv = tid >> 6;             // 16 waves
    __shared__ ull shA[KSTRIDE];         // 96 KB: 3 sorted runs
    __shared__ float4 shPB[NQ];          // 14.4 KB
    __shared__ uint32_t fidx[PRE];       // 40 KB: rank -> flat index
    __shared__ float aX1[POST], aY1[POST], aX2[POST], aY2[POST], aAr[POST];
    __shared__ int   aCl[POST];
    __shared__ float s_x1[K_WIN], s_y1[K_WIN], s_x2[K_WIN], s_y2[K_WIN];
    __shared__ int   s_cl[K_WIN];
    __shared__ uint32_t s_em[K_WIN];
    __shared__ uint32_t smx[16];
    __shared__ float sOffD;

    const float ih = target_sizes[img * 2 + 0];
    const float iw = target_sizes[img * 2 + 1];
    const float* pb = pred_boxes + (size_t)img * NQ * 4;
    const float* lg = logits + (size_t)img * NQC;
    const ull* kI = keys + (size_t)img * KSTRIDE;

    // ---- Phase 0: load 3 runs (keep reg copies) + pred_boxes ----
    ull xk[12];
    #pragma unroll
    for (int k = 0; k < 12; ++k) {
        xk[k] = kI[tid + k * 1024];
        shA[tid + k * 1024] = xk[k];
    }
    if (tid < NQ) shPB[tid] = ((const float4*)pb)[tid];
    __syncthreads();

    // ---- Phase 1: rank merge, breadth-first searches ----
    // count-of-greater in a desc 4096 array: 12 pow2 steps + 1 correction
    const int OB0[3] = {4096, 0, 0};      // other-run bases by own run id
    const int OB1[3] = {8192, 8192, 4096};
    uint32_t rnk[12];
    #pragma unroll
    for (int c4 = 0; c4 < 3; ++c4) {
        uint32_t p[8];
        #pragma unroll
        for (int j = 0; j < 8; ++j) p[j] = 0u;
        #pragma unroll
        for (int st = 0; st < 12; ++st) {
            const int s = 2048 >> st;
            ull v[8];
            #pragma unroll
            for (int j = 0; j < 8; ++j) {
                const int k = c4 * 4 + (j >> 1);
                const int ob = (j & 1) ? OB1[k >> 2] : OB0[k >> 2];
                v[j] = shA[ob + p[j] + s - 1];
            }
            #pragma unroll
            for (int j = 0; j < 8; ++j)
                if (v[j] > xk[c4 * 4 + (j >> 1)]) p[j] += (uint32_t)s;
        }
        #pragma unroll
        for (int j = 0; j < 8; ++j) {      // correction: count may be 4096
            const int k = c4 * 4 + (j >> 1);
            const int ob = (j & 1) ? OB1[k >> 2] : OB0[k >> 2];
            if (shA[ob + p[j]] > xk[k]) p[j] += 1u;
        }
        #pragma unroll
        for (int q2 = 0; q2 < 4; ++q2) {
            const int k = c4 * 4 + q2;
            rnk[k] = (uint32_t)((tid + k * 1024) & (RUNSZ - 1)) + p[2 * q2] + p[2 * q2 + 1];
        }
    }
    // scatter fidx + max-coord (over top-PRE only, matching reference)
    uint32_t lmx = 0u;
    #pragma unroll
    for (int k = 0; k < 12; ++k) {
        ull x = xk[k];
        if (x != 0ull && rnk[k] < PRE) {
            uint32_t fu = ~(uint32_t)x;
            fidx[rnk[k]] = fu;
            uint32_t q = qclamp(fu / NC);
            float4 bb = shPB[q];
            float x1 = (bb.x - 0.5f * bb.z) * iw;
            float y1 = (bb.y - 0.5f * bb.w) * ih;
            float x2 = (bb.x + 0.5f * bb.z) * iw;
            float y2 = (bb.y + 0.5f * bb.w) * ih;
            uint32_t km = fkey(fmaxf(fmaxf(x1, y1), fmaxf(x2, y2)));
            if (km > lmx) lmx = km;
        }
    }
    for (int off = 32; off > 0; off >>= 1) {
        uint32_t o = (uint32_t)__shfl_down((int)lmx, off, 64);
        if (o > lmx) lmx = o;
    }
    if (lane == 0) smx[wv] = lmx;
    __syncthreads();
    if (tid == 0) {
        uint32_t m = smx[0];
        for (int w2 = 1; w2 < 16; ++w2) if (smx[w2] > m) m = smx[w2];
        uint32_t b = (m & 0x80000000u) ? (m & 0x7FFFFFFFu) : ~m;
        sOffD = __uint_as_float(b) + 1.0f;   // max_coord + 1
    }
    __syncthreads();
    const float offD = sOffD;

    // ---- Phase 3: lazy windowed greedy. wave wv owns candidate rank base+wv ----
    int npick = 0;
    int base = 0;
    while (npick < POST) {
        if (base >= PRE) {   // active exhausted: reference repeats index 0
            uint32_t f0 = fidx[0];
            uint32_t q0 = qclamp(f0 / NC);
            uint32_t c0 = f0 - (f0 / NC) * NC;
            float4 bb = shPB[q0];
            float rx1 = (bb.x - 0.5f * bb.z) * iw;
            float ry1 = (bb.y - 0.5f * bb.w) * ih;
            float rx2 = (bb.x + 0.5f * bb.z) * iw;
            float ry2 = (bb.y + 0.5f * bb.w) * ih;
            float sc = 1.0f / (1.0f + expf(-lg[(f0 < NQC) ? f0 : 0]));
            for (int p2 = npick + tid; p2 < POST; p2 += 1024) {
                out[img * POST + p2] = sc;
                out[BS * POST + img * POST + p2] = (float)c0;
                float* ob2 = out + 2 * BS * POST + ((size_t)img * POST + p2) * 4;
                ob2[0] = rx1; ob2[1] = ry1; ob2[2] = rx2; ob2[3] = ry2;
            }
            break;
        }

        // stage A: each wave computes its candidate (wave-uniform), lane0 stages it
        const int r = base + wv;
        const bool val = (r < PRE);
        const uint32_t f = val ? fidx[r] : 0u;
        const float lgv = lg[(val && f < NQC) ? f : 0];    // issue early
        const uint32_t q = qclamp(f / NC);
        const uint32_t cc = f - (f / NC) * NC;
        float4 bb = shPB[q];
        const float x1 = (bb.x - 0.5f * bb.z) * iw;
        const float y1 = (bb.y - 0.5f * bb.w) * ih;
        const float x2 = (bb.x + 0.5f * bb.z) * iw;
        const float y2 = (bb.y + 0.5f * bb.w) * ih;
        if (lane == 0) {
            s_x1[wv] = x1; s_y1[wv] = y1; s_x2[wv] = x2; s_y2[wv] = y2;
            s_cl[wv] = val ? (int)cc : -1;
        }
        __syncthreads();

        // stage B: conflicts. offset arithmetic replicates reference (raw + o).
        const float o = (float)cc * offD;
        const float cx1 = x1 + o, cy1 = y1 + o, cx2 = x2 + o, cy2 = y2 + o;
        const float car = (cx2 - cx1) * (cy2 - cy1);
        bool cf = false;
        if (val && lane < wv && s_cl[lane] == (int)cc) {    // in-window, same class
            float jx1 = s_x1[lane] + o, jy1 = s_y1[lane] + o;
            float jx2 = s_x2[lane] + o, jy2 = s_y2[lane] + o;
            float arj = (jx2 - jx1) * (jy2 - jy1);
            float xx1 = fmaxf(jx1, cx1), yy1 = fmaxf(jy1, cy1);
            float xx2 = fminf(jx2, cx2), yy2 = fminf(jy2, cy2);
            float inter = fmaxf(xx2 - xx1, 0.0f) * fmaxf(yy2 - yy1, 0.0f);
            float uni = (arj + car) - inter;
            float iou = inter / fmaxf(uni, 1e-9f);
            cf = !(iou <= 0.7f);
        }
        uint32_t em = (uint32_t)(__ballot(cf) & 0xFFFFull);
        bool pf = false;
        for (int i2 = lane; i2 < npick; i2 += 64) {          // vs accepted picks
            if (aCl[i2] == (int)cc) {
                float jx1 = aX1[i2] + o, jy1 = aY1[i2] + o;
                float jx2 = aX2[i2] + o, jy2 = aY2[i2] + o;
                float arj = aAr[i2];
                float xx1 = fmaxf(jx1, cx1), yy1 = fmaxf(jy1, cy1);
                float xx2 = fminf(jx2, cx2), yy2 = fminf(jy2, cy2);
                float inter = fmaxf(xx2 - xx1, 0.0f) * fmaxf(yy2 - yy1, 0.0f);
                float uni = (arj + car) - inter;
                float iou = inter / fmaxf(uni, 1e-9f);
                pf |= !(iou <= 0.7f);
            }
        }
        bool anyPrior = (__ballot(pf) != 0ull);
        if (lane == 0)
            s_em[wv] = em | (anyPrior ? 0x80000000u : 0u) | (val ? 0u : 0x40000000u);
        __syncthreads();

        // stage C: uniform sequential resolution over the 16 window candidates
        uint32_t acc = 0u; int a = 0;
        const int room = POST - npick;
        #pragma unroll
        for (int w2 = 0; w2 < K_WIN; ++w2) {
            uint32_t ew = s_em[w2];
            if (!(ew & 0xC0000000u) && a < room && ((ew & 0xFFFFu & acc) == 0u)) {
                acc |= (1u << w2); ++a;
            }
        }

        // stage D: accepted waves write output + append to accepted list (parallel)
        if (((acc >> wv) & 1u) && lane == 0) {
            int p = npick + __popc(acc & ((1u << wv) - 1u));
            float sc = 1.0f / (1.0f + expf(-lgv));
            out[img * POST + p] = sc;
            out[BS * POST + img * POST + p] = (float)cc;
            float* ob2 = out + 2 * BS * POST + ((size_t)img * POST + p) * 4;
            ob2[0] = x1; ob2[1] = y1; ob2[2] = x2; ob2[3] = y2;
            aX1[p] = x1; aY1[p] = y1; aX2[p] = x2; aY2[p] = y2;
            aAr[p] = car; aCl[p] = (int)cc;
        }
        npick += a;
        base += K_WIN;
        // no end barrier needed: next iteration's stage-A barrier orders
        // stage-D accepted-list writes before stage-B reads.
    }
}

extern "C" void kernel_launch(void* const* d_in, const int* in_sizes, int n_in,
                              void* d_out, int out_size, void* d_ws, size_t ws_size,
                              hipStream_t stream) {
    const float* logits = (const float*)d_in[0];
    const float* boxes  = (const float*)d_in[1];
    const float* tsizes = (const float*)d_in[2];
    float* out = (float*)d_out;

    char* ws = (char*)d_ws;
    uint32_t* thr = (uint32_t*)(ws + WS_THR);
    ull* keys = (ull*)(ws + WS_KEYS);

    k_select<<<BS, 1024, 0, stream>>>(logits, thr);
    k_sortcompact<<<dim3(RUNS, BS), 1024, 0, stream>>>(logits, thr, keys);
    k_nms<<<BS, 1024, 0, stream>>>(keys, logits, boxes, tsizes, out);
}